// Round 1
// baseline (649.390 us; speedup 1.0000x reference)
//
#include <hip/hip_runtime.h>
#include <math.h>

#define Bb 64
#define Nn 32
#define FNf 32
#define FEe 16
#define Hh 32
#define FCc 128

__device__ __forceinline__ float sigf(float x) { return 1.0f / (1.0f + expf(-x)); }

// h[b,n,u] = x[b,n,:] @ W_emb[:,u] + b_emb[u]; msk[b,n] = (sum_f x > 0)
__global__ void k_embed(const float* __restrict__ x, const float* __restrict__ W_emb,
                        const float* __restrict__ b_emb, float* __restrict__ h,
                        float* __restrict__ msk) {
    __shared__ float xs[8][FNf];
    int tid = threadIdx.x;
    int row0 = blockIdx.x * 8;             // 8 rows of (b*N+n), grid=256
    int r = tid >> 5, u = tid & 31;
    xs[r][u] = x[(row0 + r) * FNf + u];    // 256 contiguous
    __syncthreads();
    float acc = b_emb[u];
    #pragma unroll
    for (int k = 0; k < FNf; ++k) acc += xs[r][k] * W_emb[k * Hh + u];
    h[(row0 + r) * Hh + u] = acc;
    if (u == 0) {
        float s = 0.f;
        #pragma unroll
        for (int k = 0; k < FNf; ++k) s += xs[r][k];
        msk[row0 + r] = (s > 0.f) ? 1.f : 0.f;
    }
}

// t[row,c] = relu(edge[row,:] @ W1[:,c] + b1[c]), row = b*N*N+i*N+j (65536 rows)
__global__ void k_edge_t(const float* __restrict__ edge, const float* __restrict__ W1,
                         const float* __restrict__ b1, float* __restrict__ t) {
    __shared__ float es[2][FEe];
    int tid = threadIdx.x;
    int row0 = blockIdx.x * 2;             // grid = 32768
    if (tid < 2 * FEe) es[tid >> 4][tid & 15] = edge[row0 * FEe + tid];
    __syncthreads();
    int r = tid >> 7, c = tid & 127;
    float acc = b1[c];
    #pragma unroll
    for (int k = 0; k < FEe; ++k) acc += es[r][k] * W1[k * FCc + c];
    t[(row0 + r) * FCc + c] = fmaxf(acc, 0.f);
}

// G[row, c*32+u] = sum_v W2[c, u*32+v] * h[row, v]   (row = b*N+i)
__global__ void k_G(const float* __restrict__ h, const float* __restrict__ W2,
                    float* __restrict__ G) {
    __shared__ float hs[32][Hh];
    int tid = threadIdx.x;
    int cu = blockIdx.x * 256 + tid;       // grid.x = 16 (4096 cols)
    int row0 = blockIdx.y * 32;            // grid.y = 64 (2048 rows)
    for (int k = tid; k < 32 * Hh; k += 256) hs[k >> 5][k & 31] = h[row0 * Hh + k];
    __syncthreads();
    int c = cu >> 5, u = cu & 31;
    const float* w = W2 + c * (Hh * Hh) + u * Hh;
    float wr[Hh];
    #pragma unroll
    for (int v = 0; v < Hh; ++v) wr[v] = w[v];
    for (int r = 0; r < 32; ++r) {
        const float4* h4 = (const float4*)(&hs[r][0]);
        float acc = 0.f;
        #pragma unroll
        for (int v4 = 0; v4 < Hh / 4; ++v4) {
            float4 hv = h4[v4];
            acc += wr[v4 * 4 + 0] * hv.x + wr[v4 * 4 + 1] * hv.y
                 + wr[v4 * 4 + 2] * hv.z + wr[v4 * 4 + 3] * hv.w;
        }
        G[(row0 + r) * 4096 + cu] = acc;
    }
}

// message + GRU. grid = B*4 blocks (b = bid>>2, jc = bid&3 -> 8 j's), block 256 = (j 8, u 32)
__global__ void k_msg_gru(const float* __restrict__ t, const float* __restrict__ G,
                          const float* __restrict__ h, const float* __restrict__ adj,
                          const float* __restrict__ msk, const float* __restrict__ b2,
                          const float* __restrict__ gWi, const float* __restrict__ gWh,
                          const float* __restrict__ gbi, const float* __restrict__ gbh,
                          float* __restrict__ hout) {
    __shared__ float Gs[4096];       // G[b,i,:,:] flat [c*32+u]
    __shared__ float ts[8][FCc];     // t[b,i,jrange,:]
    __shared__ float hsh[Nn][Hh];    // h[b,:,:]
    __shared__ float adjs[Nn][8];    // adj[b,:,jrange]
    __shared__ float msh[8][Hh];
    __shared__ float hsums[8][Hh];
    __shared__ float gis[8][96];
    __shared__ float ghs[8][96];
    int tid = threadIdx.x;
    int b = blockIdx.x >> 2, jc = blockIdx.x & 3;
    int j = tid >> 5, u = tid & 31;
    int jg = jc * 8 + j;
    for (int k = tid; k < Nn * Hh; k += 256) hsh[k >> 5][k & 31] = h[b * Nn * Hh + k];
    for (int k = tid; k < Nn * 8; k += 256) {
        int i = k >> 3, jj = k & 7;
        adjs[i][jj] = adj[(b * Nn + i) * Nn + jc * 8 + jj];
    }
    float macc = 0.f, hsum = 0.f;
    for (int i = 0; i < Nn; ++i) {
        __syncthreads();   // prior iteration's reads done before overwrite
        const float* gp = G + (b * Nn + i) * 4096;
        for (int k = tid; k < 4096; k += 256) Gs[k] = gp[k];
        const float* tp = t + ((b * Nn + i) * Nn + jc * 8) * FCc;
        for (int k = tid; k < 8 * FCc; k += 256) ts[k >> 7][k & 127] = tp[k];
        __syncthreads();
        float a = adjs[i][j];
        if (a != 0.f) {
            float p = 0.f;
            const float4* t4 = (const float4*)(&ts[j][0]);
            #pragma unroll 8
            for (int c4 = 0; c4 < FCc / 4; ++c4) {
                float4 tv = t4[c4];
                p += tv.x * Gs[(c4 * 4 + 0) * Hh + u];
                p += tv.y * Gs[(c4 * 4 + 1) * Hh + u];
                p += tv.z * Gs[(c4 * 4 + 2) * Hh + u];
                p += tv.w * Gs[(c4 * 4 + 3) * Hh + u];
            }
            macc += a * p;
            hsum += a * hsh[i][u];
        }
    }
    hsums[j][u] = hsum;
    __syncthreads();
    {   // b2 contribution: sum_v b2[u*32+v] * hsum[j][v]
        float bt = 0.f;
        #pragma unroll
        for (int v = 0; v < Hh; ++v) bt += b2[u * Hh + v] * hsums[j][v];
        msh[j][u] = macc + bt;
    }
    __syncthreads();
    // GRU gates (torch order r,z,n): gi = m@Wi^T+bi, gh = h@Wh^T+bh
    for (int kb = 0; kb < 3; ++kb) {
        int k = kb * 32 + u;
        float gi = gbi[k], gh = gbh[k];
        #pragma unroll
        for (int v = 0; v < Hh; ++v) {
            gi += msh[j][v] * gWi[k * Hh + v];
            gh += hsh[jg][v] * gWh[k * Hh + v];
        }
        gis[j][k] = gi;
        ghs[j][k] = gh;
    }
    __syncthreads();
    {
        float r = sigf(gis[j][u] + ghs[j][u]);
        float z = sigf(gis[j][32 + u] + ghs[j][32 + u]);
        float n = tanhf(gis[j][64 + u] + r * ghs[j][64 + u]);
        float hv = hsh[jg][u];
        float m = msk[b * Nn + jg];
        hout[(b * Nn + jg) * Hh + u] = m * ((1.f - z) * n + z * hv);
    }
}

// Set2Set readout + final fc. grid = B, block = 128
__global__ void k_s2s(const float* __restrict__ h, const float* __restrict__ msk,
                      const float* __restrict__ lWi, const float* __restrict__ lWh,
                      const float* __restrict__ lbi, const float* __restrict__ lbh,
                      const float* __restrict__ Wf, const float* __restrict__ bf,
                      float* __restrict__ out) {
    __shared__ float hsh[Nn][Hh];
    __shared__ float mskk[Nn];
    __shared__ float qs[Hh], cs[Hh], qstar[2 * Hh], gs[4 * Hh], as[Nn], es[Nn];
    int tid = threadIdx.x;
    int b = blockIdx.x;
    for (int k = tid; k < Nn * Hh; k += 128) hsh[k >> 5][k & 31] = h[b * Nn * Hh + k];
    if (tid < Nn) mskk[tid] = msk[b * Nn + tid];
    if (tid < Hh) { qs[tid] = 0.f; cs[tid] = 0.f; }
    if (tid < 2 * Hh) qstar[tid] = 0.f;
    __syncthreads();
    for (int step = 0; step < 3; ++step) {
        {   // LSTM pre-activations, k = tid (128)
            int k = tid;
            float g = lbi[k] + lbh[k];
            #pragma unroll
            for (int p = 0; p < 2 * Hh; ++p) g += qstar[p] * lWi[k * 2 * Hh + p];
            #pragma unroll
            for (int v = 0; v < Hh; ++v) g += qs[v] * lWh[k * Hh + v];
            gs[k] = g;
        }
        __syncthreads();
        if (tid < Hh) {   // gates i,f,g,o
            float ci = sigf(gs[Hh + tid]) * cs[tid] + sigf(gs[tid]) * tanhf(gs[2 * Hh + tid]);
            cs[tid] = ci;
            qs[tid] = sigf(gs[3 * Hh + tid]) * tanhf(ci);
        }
        __syncthreads();
        if (tid < Nn) {
            float e = 0.f;
            #pragma unroll
            for (int v = 0; v < Hh; ++v) e += hsh[tid][v] * qs[v];
            es[tid] = (mskk[tid] == 0.f) ? -INFINITY : e;
        }
        __syncthreads();
        if (tid < Nn) {   // softmax over 32 (lanes 0..31 of wave 0)
            float e = es[tid];
            float mx = e;
            for (int o = 16; o >= 1; o >>= 1) mx = fmaxf(mx, __shfl_xor(mx, o, 64));
            float a = expf(e - mx);
            float ssum = a;
            for (int o = 16; o >= 1; o >>= 1) ssum += __shfl_xor(ssum, o, 64);
            as[tid] = a / ssum;
        }
        __syncthreads();
        if (tid < Hh) {
            float r = 0.f;
            #pragma unroll
            for (int n = 0; n < Nn; ++n) r += as[n] * hsh[n][tid] * mskk[n];
            qstar[tid] = qs[tid];
            qstar[Hh + tid] = r;
        }
        __syncthreads();
    }
    if (tid < 2 * Hh) {   // out[b] = qstar @ Wf + bf (OUT=1), wave-0 reduce
        float v = qstar[tid] * Wf[tid];
        for (int o = 32; o >= 1; o >>= 1) v += __shfl_xor(v, o, 64);
        if (tid == 0) out[b] = v + bf[0];
    }
}

extern "C" void kernel_launch(void* const* d_in, const int* in_sizes, int n_in,
                              void* d_out, int out_size, void* d_ws, size_t ws_size,
                              hipStream_t stream) {
    const float* x    = (const float*)d_in[0];
    const float* edge = (const float*)d_in[1];
    const float* adj  = (const float*)d_in[2];
    const float* W_emb= (const float*)d_in[3];
    const float* b_emb= (const float*)d_in[4];
    const float* W1   = (const float*)d_in[5];
    const float* b1   = (const float*)d_in[6];
    const float* W2   = (const float*)d_in[7];
    const float* b2   = (const float*)d_in[8];
    const float* gWi  = (const float*)d_in[9];
    const float* gWh  = (const float*)d_in[10];
    const float* gbi  = (const float*)d_in[11];
    const float* gbh  = (const float*)d_in[12];
    const float* lWi  = (const float*)d_in[13];
    const float* lWh  = (const float*)d_in[14];
    const float* lbi  = (const float*)d_in[15];
    const float* lbh  = (const float*)d_in[16];
    const float* Wf   = (const float*)d_in[17];
    const float* bf   = (const float*)d_in[18];
    float* out = (float*)d_out;

    float* ws  = (float*)d_ws;
    float* t   = ws;                         // 64*32*32*128       = 8388608
    float* G   = t + 8388608;                // 64*32*128*32       = 8388608
    float* hA  = G + 8388608;                // 64*32*32           = 65536
    float* hB  = hA + 65536;                 //                      65536
    float* mskp = hB + 65536;                // 64*32              = 2048

    k_embed <<<256, 256, 0, stream>>>(x, W_emb, b_emb, hA, mskp);
    k_edge_t<<<32768, 256, 0, stream>>>(edge, W1, b1, t);
    float* hcur = hA;
    float* hnxt = hB;
    for (int l = 0; l < 3; ++l) {
        dim3 gG(16, 64);
        k_G<<<gG, 256, 0, stream>>>(hcur, W2, G);
        k_msg_gru<<<Bb * 4, 256, 0, stream>>>(t, G, hcur, adj, mskp, b2,
                                              gWi, gWh, gbi, gbh, hnxt);
        float* tmp = hcur; hcur = hnxt; hnxt = tmp;
    }
    k_s2s<<<Bb, 128, 0, stream>>>(hcur, mskp, lWi, lWh, lbi, lbh, Wf, bf, out);
}

// Round 2
// 190.909 us; speedup vs baseline: 3.4016x; 3.4016x over previous
//
#include <hip/hip_runtime.h>
#include <hip/hip_bf16.h>
#include <math.h>

#define Bb 64
#define Nn 32
#define FNf 32
#define FEe 16
#define Hh 32
#define FCc 128

typedef __attribute__((ext_vector_type(8))) short bf16x8;
typedef __attribute__((ext_vector_type(16))) float f32x16;

__device__ __forceinline__ float sigf(float x) { return 1.0f / (1.0f + expf(-x)); }

// h[b,n,u] = x[b,n,:] @ W_emb[:,u] + b_emb[u]; msk[b,n] = (sum_f x > 0)
__global__ void k_embed(const float* __restrict__ x, const float* __restrict__ W_emb,
                        const float* __restrict__ b_emb, float* __restrict__ h,
                        __hip_bfloat16* __restrict__ h_bf, float* __restrict__ msk) {
    __shared__ float xs[8][FNf];
    int tid = threadIdx.x;
    int row0 = blockIdx.x * 8;             // 8 rows of (b*N+n), grid=256
    int r = tid >> 5, u = tid & 31;
    xs[r][u] = x[(row0 + r) * FNf + u];
    __syncthreads();
    float acc = b_emb[u];
    #pragma unroll
    for (int k = 0; k < FNf; ++k) acc += xs[r][k] * W_emb[k * Hh + u];
    h[(row0 + r) * Hh + u] = acc;
    h_bf[(row0 + r) * Hh + u] = __float2bfloat16(acc);
    if (u == 0) {
        float s = 0.f;
        #pragma unroll
        for (int k = 0; k < FNf; ++k) s += xs[r][k];
        msk[row0 + r] = (s > 0.f) ? 1.f : 0.f;
    }
}

// t[row,c] = relu(edge[row,:] @ W1[:,c] + b1[c])  (bf16 out), row = b*N*N+i*N+j
__global__ void k_edge_t(const float* __restrict__ edge, const float* __restrict__ W1,
                         const float* __restrict__ b1, __hip_bfloat16* __restrict__ t) {
    __shared__ float es[8][FEe];
    int tid = threadIdx.x;
    long row0 = (long)blockIdx.x * 8;      // grid = 8192
    if (tid < 128) es[tid >> 4][tid & 15] = edge[row0 * FEe + tid];
    __syncthreads();
    #pragma unroll
    for (int q = 0; q < 4; ++q) {
        int idx = q * 256 + tid;
        int r = idx >> 7, c = idx & 127;
        float acc = b1[c];
        #pragma unroll
        for (int k = 0; k < FEe; ++k) acc += es[r][k] * W1[k * FCc + c];
        t[(row0 + r) * FCc + c] = __float2bfloat16(fmaxf(acc, 0.f));
    }
}

// BT[n][v] = W2[c = n&127][(n>>7)*32 + v]  (bf16), n = u*128+c flat 0..4095
__global__ void k_prepBT(const float* __restrict__ W2, __hip_bfloat16* __restrict__ BT) {
    int idx = blockIdx.x * 256 + threadIdx.x;   // grid = 512 -> 131072
    int n = idx >> 5, v = idx & 31;
    BT[idx] = __float2bfloat16(W2[(n & 127) * (Hh * Hh) + (n >> 7) * Hh + v]);
}

// GT[row][n] = sum_v h[row][v] * BT[n][v]  : GEMM M=2048 N=4096 K=32 via MFMA
// wave per 32x32 tile; A row=l&31,k=(l>>5)*8+e ; B col=l&31
__global__ void k_Gmfma(const __hip_bfloat16* __restrict__ hbf,
                        const __hip_bfloat16* __restrict__ BT,
                        __hip_bfloat16* __restrict__ GT) {
    int tid = threadIdx.x;
    int w = tid >> 6, l = tid & 63;
    int gwid = blockIdx.x * 4 + w;         // grid = 2048 -> 8192 waves
    int ntile = gwid & 127, mtile = gwid >> 7;
    int lid = l & 31, kh = l >> 5;
    const short* ap = (const short*)hbf + ((long)(mtile * 32 + lid)) * Hh + kh * 8;
    const short* bp = (const short*)BT + ((long)(ntile * 32 + lid)) * Hh + kh * 8;
    f32x16 acc = {};
    bf16x8 a0 = *(const bf16x8*)(ap);
    bf16x8 b0 = *(const bf16x8*)(bp);
    acc = __builtin_amdgcn_mfma_f32_32x32x16_bf16(a0, b0, acc, 0, 0, 0);
    bf16x8 a1 = *(const bf16x8*)(ap + 16);
    bf16x8 b1v = *(const bf16x8*)(bp + 16);
    acc = __builtin_amdgcn_mfma_f32_32x32x16_bf16(a1, b1v, acc, 0, 0, 0);
    __hip_bfloat16* gp = GT + (long)(mtile * 32) * 4096 + ntile * 32 + lid;
    #pragma unroll
    for (int r = 0; r < 16; ++r) {
        int crow = (r & 3) + 8 * (r >> 2) + 4 * kh;
        gp[(long)crow * 4096] = __float2bfloat16(acc[r]);
    }
}

// P[b,ig][j][u] = sum_{i in ig*4..+3} adj[b,i,j] * (T_{b,i} @ G_{b,i})[j][u]
// wave per (b,i), adj folded into A rows (adj in {0,1} -> exact), block-reduce 4 waves
__global__ void k_msg(const __hip_bfloat16* __restrict__ t,
                      const __hip_bfloat16* __restrict__ GT,
                      const float* __restrict__ adj, float* __restrict__ part) {
    __shared__ float red[4][1024];
    int tid = threadIdx.x;
    int w = tid >> 6, l = tid & 63;
    int b = blockIdx.x >> 3, ig = blockIdx.x & 7;   // grid = 512
    int i = ig * 4 + w;
    int lid = l & 31, kh = l >> 5;
    int bi = b * Nn + i;
    const short* tp = (const short*)t + ((long)bi * Nn + lid) * FCc + kh * 8;
    const short* gp = (const short*)GT + (long)bi * 4096 + lid * FCc + kh * 8;
    float a = adj[bi * Nn + lid];
    f32x16 acc = {};
    bf16x8 zf = {};
    #pragma unroll
    for (int kk = 0; kk < 8; ++kk) {
        bf16x8 af = *(const bf16x8*)(tp + kk * 16);
        bf16x8 bf_ = *(const bf16x8*)(gp + kk * 16);
        if (a == 0.f) af = zf;
        acc = __builtin_amdgcn_mfma_f32_32x32x16_bf16(af, bf_, acc, 0, 0, 0);
    }
    #pragma unroll
    for (int r = 0; r < 16; ++r) {
        int crow = (r & 3) + 8 * (r >> 2) + 4 * kh;
        red[w][crow * 32 + lid] = acc[r];
    }
    __syncthreads();
    for (int k = tid; k < 1024; k += 256) {
        part[(long)blockIdx.x * 1024 + k] = red[0][k] + red[1][k] + red[2][k] + red[3][k];
    }
}

// reduce partials + b2 term + GRU. grid = B, block = 1024 (j = tid>>5, u = tid&31)
__global__ void k_gru(const float* __restrict__ part, const float* __restrict__ h,
                      const float* __restrict__ adj, const float* __restrict__ msk,
                      const float* __restrict__ b2,
                      const float* __restrict__ gWi, const float* __restrict__ gWh,
                      const float* __restrict__ gbi, const float* __restrict__ gbh,
                      float* __restrict__ hout, __hip_bfloat16* __restrict__ hout_bf) {
    __shared__ float hsh[1024], adjs[1024], hsumL[1024], mL[1024];
    int b = blockIdx.x, tid = threadIdx.x;
    int j = tid >> 5, u = tid & 31;
    hsh[tid] = h[b * 1024 + tid];
    adjs[tid] = adj[b * 1024 + tid];
    float ps = 0.f;
    #pragma unroll
    for (int ig = 0; ig < 8; ++ig) ps += part[((long)b * 8 + ig) * 1024 + tid];
    __syncthreads();
    float hs = 0.f;      // hsum[j][v=u] = sum_i adj[b,i,j]*h[b,i,u]
    #pragma unroll
    for (int i = 0; i < 32; ++i) hs += adjs[i * 32 + j] * hsh[i * 32 + u];
    hsumL[tid] = hs;
    __syncthreads();
    float m = ps;        // + b2 contribution
    #pragma unroll
    for (int v = 0; v < 32; ++v) m += b2[u * 32 + v] * hsumL[j * 32 + v];
    mL[tid] = m;
    __syncthreads();
    float gi[3], gh[3];
    #pragma unroll
    for (int kb = 0; kb < 3; ++kb) {
        int k = kb * 32 + u;
        float a = gbi[k], c = gbh[k];
        #pragma unroll
        for (int v = 0; v < 32; ++v) {
            a += mL[j * 32 + v] * gWi[k * 32 + v];
            c += hsh[j * 32 + v] * gWh[k * 32 + v];
        }
        gi[kb] = a; gh[kb] = c;
    }
    float r = sigf(gi[0] + gh[0]);
    float z = sigf(gi[1] + gh[1]);
    float n = tanhf(gi[2] + r * gh[2]);
    float hv = hsh[tid];
    float mm = msk[b * 32 + j];
    float res = mm * ((1.f - z) * n + z * hv);
    hout[b * 1024 + tid] = res;
    hout_bf[b * 1024 + tid] = __float2bfloat16(res);
}

// Set2Set readout + final fc. grid = B, block = 128
__global__ void k_s2s(const float* __restrict__ h, const float* __restrict__ msk,
                      const float* __restrict__ lWi, const float* __restrict__ lWh,
                      const float* __restrict__ lbi, const float* __restrict__ lbh,
                      const float* __restrict__ Wf, const float* __restrict__ bf,
                      float* __restrict__ out) {
    __shared__ float hsh[Nn][Hh];
    __shared__ float mskk[Nn];
    __shared__ float qs[Hh], cs[Hh], qstar[2 * Hh], gs[4 * Hh], as[Nn], es[Nn];
    int tid = threadIdx.x;
    int b = blockIdx.x;
    for (int k = tid; k < Nn * Hh; k += 128) hsh[k >> 5][k & 31] = h[b * Nn * Hh + k];
    if (tid < Nn) mskk[tid] = msk[b * Nn + tid];
    if (tid < Hh) { qs[tid] = 0.f; cs[tid] = 0.f; }
    if (tid < 2 * Hh) qstar[tid] = 0.f;
    __syncthreads();
    for (int step = 0; step < 3; ++step) {
        {
            int k = tid;
            float g = lbi[k] + lbh[k];
            #pragma unroll
            for (int p = 0; p < 2 * Hh; ++p) g += qstar[p] * lWi[k * 2 * Hh + p];
            #pragma unroll
            for (int v = 0; v < Hh; ++v) g += qs[v] * lWh[k * Hh + v];
            gs[k] = g;
        }
        __syncthreads();
        if (tid < Hh) {
            float ci = sigf(gs[Hh + tid]) * cs[tid] + sigf(gs[tid]) * tanhf(gs[2 * Hh + tid]);
            cs[tid] = ci;
            qs[tid] = sigf(gs[3 * Hh + tid]) * tanhf(ci);
        }
        __syncthreads();
        if (tid < Nn) {
            float e = 0.f;
            #pragma unroll
            for (int v = 0; v < Hh; ++v) e += hsh[tid][v] * qs[v];
            es[tid] = (mskk[tid] == 0.f) ? -INFINITY : e;
        }
        __syncthreads();
        if (tid < Nn) {
            float e = es[tid];
            float mx = e;
            for (int o = 16; o >= 1; o >>= 1) mx = fmaxf(mx, __shfl_xor(mx, o, 64));
            float a = expf(e - mx);
            float ssum = a;
            for (int o = 16; o >= 1; o >>= 1) ssum += __shfl_xor(ssum, o, 64);
            as[tid] = a / ssum;
        }
        __syncthreads();
        if (tid < Hh) {
            float r = 0.f;
            #pragma unroll
            for (int n = 0; n < Nn; ++n) r += as[n] * hsh[n][tid] * mskk[n];
            qstar[tid] = qs[tid];
            qstar[Hh + tid] = r;
        }
        __syncthreads();
    }
    if (tid < 2 * Hh) {
        float v = qstar[tid] * Wf[tid];
        for (int o = 32; o >= 1; o >>= 1) v += __shfl_xor(v, o, 64);
        if (tid == 0) out[b] = v + bf[0];
    }
}

extern "C" void kernel_launch(void* const* d_in, const int* in_sizes, int n_in,
                              void* d_out, int out_size, void* d_ws, size_t ws_size,
                              hipStream_t stream) {
    const float* x    = (const float*)d_in[0];
    const float* edge = (const float*)d_in[1];
    const float* adj  = (const float*)d_in[2];
    const float* W_emb= (const float*)d_in[3];
    const float* b_emb= (const float*)d_in[4];
    const float* W1   = (const float*)d_in[5];
    const float* b1   = (const float*)d_in[6];
    const float* W2   = (const float*)d_in[7];
    const float* b2   = (const float*)d_in[8];
    const float* gWi  = (const float*)d_in[9];
    const float* gWh  = (const float*)d_in[10];
    const float* gbi  = (const float*)d_in[11];
    const float* gbh  = (const float*)d_in[12];
    const float* lWi  = (const float*)d_in[13];
    const float* lWh  = (const float*)d_in[14];
    const float* lbi  = (const float*)d_in[15];
    const float* lbh  = (const float*)d_in[16];
    const float* Wf   = (const float*)d_in[17];
    const float* bf   = (const float*)d_in[18];
    float* out = (float*)d_out;

    __hip_bfloat16* t_bf = (__hip_bfloat16*)d_ws;       // 8388608 bf16
    __hip_bfloat16* GT   = t_bf + 8388608;              // 8388608 bf16
    __hip_bfloat16* BT   = GT + 8388608;                // 131072 bf16
    __hip_bfloat16* hbfA = BT + 131072;                 // 65536 bf16
    __hip_bfloat16* hbfB = hbfA + 65536;                // 65536 bf16
    float* hA   = (float*)(hbfB + 65536);               // 65536 f32
    float* hB   = hA + 65536;                           // 65536 f32
    float* mskp = hB + 65536;                           // 2048 f32
    float* part = mskp + 2048;                          // 524288 f32

    k_prepBT<<<512, 256, 0, stream>>>(W2, BT);
    k_embed <<<256, 256, 0, stream>>>(x, W_emb, b_emb, hA, hbfA, mskp);
    k_edge_t<<<8192, 256, 0, stream>>>(edge, W1, b1, t_bf);
    float* hcur = hA; float* hnxt = hB;
    __hip_bfloat16* hbcur = hbfA; __hip_bfloat16* hbnxt = hbfB;
    for (int l = 0; l < 3; ++l) {
        k_Gmfma<<<2048, 256, 0, stream>>>(hbcur, BT, GT);
        k_msg  <<<512, 256, 0, stream>>>(t_bf, GT, adj, part);
        k_gru  <<<64, 1024, 0, stream>>>(part, hcur, adj, mskp, b2,
                                         gWi, gWh, gbi, gbh, hnxt, hbnxt);
        float* tf = hcur; hcur = hnxt; hnxt = tf;
        __hip_bfloat16* tb = hbcur; hbcur = hbnxt; hbnxt = tb;
    }
    k_s2s<<<Bb, 128, 0, stream>>>(hcur, mskp, lWi, lWh, lbi, lbh, Wf, bf, out);
}

// Round 4
// 174.939 us; speedup vs baseline: 3.7121x; 1.0913x over previous
//
#include <hip/hip_runtime.h>
#include <hip/hip_bf16.h>
#include <math.h>

typedef __attribute__((ext_vector_type(8))) short bf16x8;
typedef __attribute__((ext_vector_type(16))) float f32x16;

__device__ __forceinline__ float sigf(float x) { return 1.0f / (1.0f + expf(-x)); }

// prep: ta[row=b,i,j][c] = adj[b,i,j]*relu(edge@W1+b1)  (bf16),
//       h = x@W_emb+b_emb (+bf16 shadow), msk, BT[n][v] = W2[n&127][(n>>7)*32+v]
__global__ __launch_bounds__(256, 2) void k_prep(
    const float* __restrict__ edge, const float* __restrict__ adj,
    const float* __restrict__ W1, const float* __restrict__ b1,
    const float* __restrict__ x, const float* __restrict__ W_emb,
    const float* __restrict__ b_emb, const float* __restrict__ W2,
    __hip_bfloat16* __restrict__ ta, __hip_bfloat16* __restrict__ BT,
    float* __restrict__ h, __hip_bfloat16* __restrict__ hbf, float* __restrict__ msk) {
    __shared__ float xs[256];
    const int tid = threadIdx.x, bid = blockIdx.x;
    const int c = tid & 127, g = tid >> 7;
    float wr[16];
    #pragma unroll
    for (int v = 0; v < 16; ++v) wr[v] = W1[v * 128 + c];
    const float b1c = b1[c];
    const int row0 = bid * 128 + g * 64;
    for (int rr = 0; rr < 64; ++rr) {
        int row = row0 + rr;
        const float4* e4 = (const float4*)(edge + (long)row * 16);
        float acc = b1c;
        #pragma unroll
        for (int q = 0; q < 4; ++q) {
            float4 ev = e4[q];
            acc += ev.x * wr[q * 4] + ev.y * wr[q * 4 + 1]
                 + ev.z * wr[q * 4 + 2] + ev.w * wr[q * 4 + 3];
        }
        float av = adj[row];
        ta[(long)row * 128 + c] = __float2bfloat16(av * fmaxf(acc, 0.f));
    }
    if (bid < 256) {            // embed: 8 rows of (b*N+n)
        int r = tid >> 5, u = tid & 31;
        int rowe = bid * 8 + r;
        xs[tid] = x[bid * 256 + tid];
        __syncthreads();
        float acc = b_emb[u];
        #pragma unroll
        for (int k = 0; k < 32; ++k) acc += xs[r * 32 + k] * W_emb[k * 32 + u];
        h[rowe * 32 + u] = acc;
        hbf[rowe * 32 + u] = __float2bfloat16(acc);
        if (u == 0) {
            float s = 0.f;
            #pragma unroll
            for (int k = 0; k < 32; ++k) s += xs[r * 32 + k];
            msk[rowe] = (s > 0.f) ? 1.f : 0.f;
        }
    } else if (bid < 384) {     // BT
        int base = (bid - 256) * 1024;
        #pragma unroll
        for (int q = 0; q < 4; ++q) {
            int idx = base + q * 256 + tid;
            int n = idx >> 5, v = idx & 31;
            BT[idx] = __float2bfloat16(W2[(n & 127) * 1024 + (n >> 7) * 32 + v]);
        }
    }
}

// per-layer: G_{b,i} (i = ig*4..+3) into LDS via M=4-padded MFMA, then
// msg MFMA P += T@G from LDS (XOR-swizzled), block-reduce 4 waves -> part
__global__ __launch_bounds__(256, 2) void k_layer(
    const __hip_bfloat16* __restrict__ hbf, const __hip_bfloat16* __restrict__ BT,
    const __hip_bfloat16* __restrict__ ta, float* __restrict__ part) {
    __shared__ __align__(16) char smem[32768];
    const int tid = threadIdx.x, bid = blockIdx.x;
    const int w = tid >> 6, l = tid & 63, lid = l & 31, kh = l >> 5;
    const int b = bid >> 3, ig = bid & 7;
    // ---- G phase ----
    {
        const short* hp = (const short*)hbf + ((b * 32 + ig * 4 + (lid & 3)) * 32 + kh * 8);
        bf16x8 a0 = *(const bf16x8*)hp;
        bf16x8 a1 = *(const bf16x8*)(hp + 16);
        for (int q = 0; q < 32; ++q) {
            int nt = w * 32 + q;
            const short* bp = (const short*)BT + ((nt * 32 + lid) * 32 + kh * 8);
            bf16x8 b0 = *(const bf16x8*)bp;
            bf16x8 b1v = *(const bf16x8*)(bp + 16);
            f32x16 accg = {};
            accg = __builtin_amdgcn_mfma_f32_32x32x16_bf16(a0, b0, accg, 0, 0, 0);
            accg = __builtin_amdgcn_mfma_f32_32x32x16_bf16(a1, b1v, accg, 0, 0, 0);
            if (kh == 0) {
                int n = nt * 32 + lid;
                int u = n >> 7, cc = n & 127;
                int byteoff = (u * 256 + cc * 2) ^ ((u & 15) << 4);
                #pragma unroll
                for (int r = 0; r < 4; ++r)   // crow = r for kh=0 -> i-slot r
                    *(__hip_bfloat16*)(smem + r * 8192 + byteoff) = __float2bfloat16(accg[r]);
            }
        }
    }
    __syncthreads();
    // ---- msg phase: wave w handles i = ig*4+w ----
    {
        long bi = b * 32 + ig * 4 + w;
        const short* tp = (const short*)ta + (bi * 32 + lid) * 128 + kh * 8;
        char* gs = smem + w * 8192;
        f32x16 acc = {};
        #pragma unroll
        for (int kk = 0; kk < 8; ++kk) {
            bf16x8 af = *(const bf16x8*)(tp + kk * 16);
            int byteoff = (lid * 256 + kh * 16 + kk * 32) ^ ((lid & 15) << 4);
            bf16x8 bfr = *(const bf16x8*)(gs + byteoff);
            acc = __builtin_amdgcn_mfma_f32_32x32x16_bf16(af, bfr, acc, 0, 0, 0);
        }
        float* red = (float*)(smem + w * 8192);   // own slot only; deps order reads first
        #pragma unroll
        for (int r = 0; r < 16; ++r) {
            int crow = (r & 3) + 8 * (r >> 2) + 4 * kh;
            red[crow * 32 + lid] = acc[r];
        }
    }
    __syncthreads();
    {
        float* r0 = (float*)smem;
        for (int k = tid; k < 1024; k += 256)
            part[(long)bid * 1024 + k] = r0[k] + r0[2048 + k] + r0[4096 + k] + r0[6144 + k];
    }
}

// reduce partials + b2 term + GRU (block per b, 1024 thr = 32j x 32u);
// final_: fuse Set2Set + output fc
__global__ __launch_bounds__(1024, 1) void k_gru(
    const float* __restrict__ part, const float* __restrict__ h,
    const float* __restrict__ adj, const float* __restrict__ msk,
    const float* __restrict__ b2,
    const float* __restrict__ gWi, const float* __restrict__ gWh,
    const float* __restrict__ gbi, const float* __restrict__ gbh,
    float* __restrict__ hout, __hip_bfloat16* __restrict__ hout_bf,
    const float* __restrict__ lWi, const float* __restrict__ lWh,
    const float* __restrict__ lbi, const float* __restrict__ lbh,
    const float* __restrict__ Wf, const float* __restrict__ bf,
    float* __restrict__ out, int final_) {
    __shared__ float hsh[1024], adjs[1024], hsumL[1024], mL[1024];
    __shared__ float aux[352];
    int b = blockIdx.x, tid = threadIdx.x;
    int j = tid >> 5, u = tid & 31;
    hsh[tid] = h[b * 1024 + tid];
    adjs[tid] = adj[b * 1024 + tid];
    float ps = 0.f;
    #pragma unroll
    for (int ig = 0; ig < 8; ++ig) ps += part[((long)b * 8 + ig) * 1024 + tid];
    __syncthreads();
    float hs = 0.f;      // hsum[j][u] = sum_i adj[b,i,j]*h[b,i,u]
    #pragma unroll
    for (int i = 0; i < 32; ++i) hs += adjs[i * 32 + j] * hsh[i * 32 + u];
    hsumL[tid] = hs;
    __syncthreads();
    float m = ps;
    #pragma unroll
    for (int v = 0; v < 32; ++v) m += b2[u * 32 + v] * hsumL[j * 32 + v];
    mL[tid] = m;
    __syncthreads();
    float gi[3], gh[3];
    #pragma unroll
    for (int kb = 0; kb < 3; ++kb) {
        int k = kb * 32 + u;
        float a = gbi[k], c = gbh[k];
        #pragma unroll
        for (int v = 0; v < 32; ++v) {
            a += mL[j * 32 + v] * gWi[k * 32 + v];
            c += hsh[j * 32 + v] * gWh[k * 32 + v];
        }
        gi[kb] = a; gh[kb] = c;
    }
    float r = sigf(gi[0] + gh[0]);
    float z = sigf(gi[1] + gh[1]);
    float n = tanhf(gi[2] + r * gh[2]);
    float hv = hsh[tid];
    float mm = msk[b * 32 + j];
    float res = mm * ((1.f - z) * n + z * hv);
    if (!final_) {
        hout[b * 1024 + tid] = res;
        hout_bf[b * 1024 + tid] = __float2bfloat16(res);
        return;
    }
    // ---- Set2Set + fc, h_new kept in LDS (reuse hsumL; all reads done) ----
    hsumL[tid] = res;
    float* hn = hsumL;
    float* mskk = aux;        float* qs = aux + 32;  float* cs2 = aux + 64;
    float* qstar = aux + 96;  float* gsv = aux + 160; float* asv = aux + 288;
    if (tid < 32) { mskk[tid] = msk[b * 32 + tid]; qs[tid] = 0.f; cs2[tid] = 0.f; }
    if (tid < 64) qstar[tid] = 0.f;
    __syncthreads();
    for (int step = 0; step < 3; ++step) {
        if (tid < 128) {
            float g = lbi[tid] + lbh[tid];
            #pragma unroll
            for (int pp = 0; pp < 64; ++pp) g += qstar[pp] * lWi[tid * 64 + pp];
            #pragma unroll
            for (int v = 0; v < 32; ++v) g += qs[v] * lWh[tid * 32 + v];
            gsv[tid] = g;
        }
        __syncthreads();
        if (tid < 32) {
            float ci = sigf(gsv[32 + tid]) * cs2[tid] + sigf(gsv[tid]) * tanhf(gsv[64 + tid]);
            cs2[tid] = ci;
            qs[tid] = sigf(gsv[96 + tid]) * tanhf(ci);
        }
        __syncthreads();
        if (tid < 32) {
            float e = 0.f;
            #pragma unroll
            for (int v = 0; v < 32; ++v) e += hn[tid * 32 + v] * qs[v];
            e = (mskk[tid] == 0.f) ? -INFINITY : e;
            float mx = e;
            for (int o = 16; o >= 1; o >>= 1) mx = fmaxf(mx, __shfl_xor(mx, o, 64));
            float a = expf(e - mx);
            float ss = a;
            for (int o = 16; o >= 1; o >>= 1) ss += __shfl_xor(ss, o, 64);
            asv[tid] = a / ss;
        }
        __syncthreads();
        if (tid < 32) {
            float rr = 0.f;
            #pragma unroll
            for (int nn = 0; nn < 32; ++nn) rr += asv[nn] * hn[nn * 32 + tid] * mskk[nn];
            qstar[tid] = qs[tid];
            qstar[32 + tid] = rr;
        }
        __syncthreads();
    }
    if (tid < 64) {
        float v = qstar[tid] * Wf[tid];
        for (int o = 32; o >= 1; o >>= 1) v += __shfl_xor(v, o, 64);
        if (tid == 0) out[b] = v + bf[0];
    }
}

extern "C" void kernel_launch(void* const* d_in, const int* in_sizes, int n_in,
                              void* d_out, int out_size, void* d_ws, size_t ws_size,
                              hipStream_t stream) {
    const float* x    = (const float*)d_in[0];
    const float* edge = (const float*)d_in[1];
    const float* adj  = (const float*)d_in[2];
    const float* W_emb= (const float*)d_in[3];
    const float* b_emb= (const float*)d_in[4];
    const float* W1   = (const float*)d_in[5];
    const float* b1   = (const float*)d_in[6];
    const float* W2   = (const float*)d_in[7];
    const float* b2   = (const float*)d_in[8];
    const float* gWi  = (const float*)d_in[9];
    const float* gWh  = (const float*)d_in[10];
    const float* gbi  = (const float*)d_in[11];
    const float* gbh  = (const float*)d_in[12];
    const float* lWi  = (const float*)d_in[13];
    const float* lWh  = (const float*)d_in[14];
    const float* lbi  = (const float*)d_in[15];
    const float* lbh  = (const float*)d_in[16];
    const float* Wf   = (const float*)d_in[17];
    const float* bf   = (const float*)d_in[18];
    float* out = (float*)d_out;

    __hip_bfloat16* ta   = (__hip_bfloat16*)d_ws;       // 8388608 bf16
    __hip_bfloat16* BT   = ta + 8388608;                // 131072 bf16
    __hip_bfloat16* hbfA = BT + 131072;                 // 65536 bf16
    __hip_bfloat16* hbfB = hbfA + 65536;                // 65536 bf16
    float* hA   = (float*)(hbfB + 65536);               // 65536 f32
    float* hB   = hA + 65536;                           // 65536 f32
    float* mskp = hB + 65536;                           // 2048 f32
    float* part = mskp + 2048;                          // 524288 f32

    k_prep<<<512, 256, 0, stream>>>(edge, adj, W1, b1, x, W_emb, b_emb, W2,
                                    ta, BT, hA, hbfA, mskp);
    float* hcur = hA; float* hnxt = hB;
    __hip_bfloat16* hbcur = hbfA; __hip_bfloat16* hbnxt = hbfB;
    for (int l = 0; l < 3; ++l) {
        k_layer<<<512, 256, 0, stream>>>(hbcur, BT, ta, part);
        k_gru<<<64, 1024, 0, stream>>>(part, hcur, adj, mskp, b2,
                                       gWi, gWh, gbi, gbh, hnxt, hbnxt,
                                       lWi, lWh, lbi, lbh, Wf, bf, out,
                                       (l == 2) ? 1 : 0);
        float* tf = hcur; hcur = hnxt; hnxt = tf;
        __hip_bfloat16* tb = hbcur; hbcur = hbnxt; hbnxt = tb;
    }
}

// Round 5
// 128.619 us; speedup vs baseline: 5.0489x; 1.3601x over previous
//
#include <hip/hip_runtime.h>
#include <hip/hip_bf16.h>
#include <math.h>

typedef __attribute__((ext_vector_type(8))) short bf16x8;
typedef __attribute__((ext_vector_type(16))) float f32x16;

__device__ __forceinline__ float sigf(float x) { return 1.0f / (1.0f + expf(-x)); }

// prep: ta[row=b,i,j][c] = adj[b,i,j]*relu(edge@W1+b1)  (bf16),
//       h = x@W_emb+b_emb (+bf16 shadow), msk, BT[n][v] = W2[n&127][(n>>7)*32+v],
//       transposed small weights for k_gru/k_s2s.
__global__ __launch_bounds__(256, 2) void k_prep(
    const float* __restrict__ edge, const float* __restrict__ adj,
    const float* __restrict__ W1, const float* __restrict__ b1,
    const float* __restrict__ x, const float* __restrict__ W_emb,
    const float* __restrict__ b_emb, const float* __restrict__ W2,
    const float* __restrict__ gWi, const float* __restrict__ gWh,
    const float* __restrict__ b2, const float* __restrict__ lWi,
    const float* __restrict__ lWh,
    __hip_bfloat16* __restrict__ ta, __hip_bfloat16* __restrict__ BT,
    float* __restrict__ h, __hip_bfloat16* __restrict__ hbf, float* __restrict__ msk,
    float* __restrict__ gWiT, float* __restrict__ gWhT, float* __restrict__ b2T,
    float* __restrict__ lWiT, float* __restrict__ lWhT) {
    __shared__ float xs[256];
    const int tid = threadIdx.x, bid = blockIdx.x;
    const int c = tid & 127, g = tid >> 7;
    float wr[16];
    #pragma unroll
    for (int v = 0; v < 16; ++v) wr[v] = W1[v * 128 + c];
    const float b1c = b1[c];
    const int row0 = bid * 128 + g * 64;
    for (int rr = 0; rr < 64; ++rr) {
        int row = row0 + rr;
        const float4* e4 = (const float4*)(edge + (long)row * 16);
        float acc = b1c;
        #pragma unroll
        for (int q = 0; q < 4; ++q) {
            float4 ev = e4[q];
            acc += ev.x * wr[q * 4] + ev.y * wr[q * 4 + 1]
                 + ev.z * wr[q * 4 + 2] + ev.w * wr[q * 4 + 3];
        }
        float av = adj[row];
        ta[(long)row * 128 + c] = __float2bfloat16(av * fmaxf(acc, 0.f));
    }
    if (bid < 256) {            // embed: 8 rows of (b*N+n)
        int r = tid >> 5, u = tid & 31;
        int rowe = bid * 8 + r;
        xs[tid] = x[bid * 256 + tid];
        __syncthreads();
        float acc = b_emb[u];
        #pragma unroll
        for (int k = 0; k < 32; ++k) acc += xs[r * 32 + k] * W_emb[k * 32 + u];
        h[rowe * 32 + u] = acc;
        hbf[rowe * 32 + u] = __float2bfloat16(acc);
        if (u == 0) {
            float s = 0.f;
            #pragma unroll
            for (int k = 0; k < 32; ++k) s += xs[r * 32 + k];
            msk[rowe] = (s > 0.f) ? 1.f : 0.f;
        }
    } else if (bid < 384) {     // BT
        int base = (bid - 256) * 1024;
        #pragma unroll
        for (int q = 0; q < 4; ++q) {
            int idx = base + q * 256 + tid;
            int n = idx >> 5, v = idx & 31;
            BT[idx] = __float2bfloat16(W2[(n & 127) * 1024 + (n >> 7) * 32 + v]);
        }
    } else if (bid == 384) {    // transposed weights (coalesced reads, scattered writes)
        for (int idx = tid; idx < 3072; idx += 256) gWiT[(idx & 31) * 96 + (idx >> 5)] = gWi[idx];
        for (int idx = tid; idx < 3072; idx += 256) gWhT[(idx & 31) * 96 + (idx >> 5)] = gWh[idx];
        for (int idx = tid; idx < 1024; idx += 256) b2T[(idx & 31) * 32 + (idx >> 5)] = b2[idx];
        for (int idx = tid; idx < 8192; idx += 256) lWiT[(idx & 63) * 128 + (idx >> 6)] = lWi[idx];
        for (int idx = tid; idx < 4096; idx += 256) lWhT[(idx & 31) * 128 + (idx >> 5)] = lWh[idx];
    }
}

// per-layer: G_{b,i} (i = ig*4..+3) into LDS via M=4-padded MFMA, then
// msg MFMA P += T@G from LDS (XOR-swizzled), block-reduce 4 waves -> part
__global__ __launch_bounds__(256, 2) void k_layer(
    const __hip_bfloat16* __restrict__ hbf, const __hip_bfloat16* __restrict__ BT,
    const __hip_bfloat16* __restrict__ ta, float* __restrict__ part) {
    __shared__ __align__(16) char smem[32768];
    const int tid = threadIdx.x, bid = blockIdx.x;
    const int w = tid >> 6, l = tid & 63, lid = l & 31, kh = l >> 5;
    const int b = bid >> 3, ig = bid & 7;
    {
        const short* hp = (const short*)hbf + ((b * 32 + ig * 4 + (lid & 3)) * 32 + kh * 8);
        bf16x8 a0 = *(const bf16x8*)hp;
        bf16x8 a1 = *(const bf16x8*)(hp + 16);
        for (int q = 0; q < 32; ++q) {
            int nt = w * 32 + q;
            const short* bp = (const short*)BT + ((nt * 32 + lid) * 32 + kh * 8);
            bf16x8 b0 = *(const bf16x8*)bp;
            bf16x8 b1v = *(const bf16x8*)(bp + 16);
            f32x16 accg = {};
            accg = __builtin_amdgcn_mfma_f32_32x32x16_bf16(a0, b0, accg, 0, 0, 0);
            accg = __builtin_amdgcn_mfma_f32_32x32x16_bf16(a1, b1v, accg, 0, 0, 0);
            if (kh == 0) {
                int n = nt * 32 + lid;
                int u = n >> 7, cc = n & 127;
                int byteoff = (u * 256 + cc * 2) ^ ((u & 15) << 4);
                #pragma unroll
                for (int r = 0; r < 4; ++r)
                    *(__hip_bfloat16*)(smem + r * 8192 + byteoff) = __float2bfloat16(accg[r]);
            }
        }
    }
    __syncthreads();
    {
        long bi = b * 32 + ig * 4 + w;
        const short* tp = (const short*)ta + (bi * 32 + lid) * 128 + kh * 8;
        char* gs = smem + w * 8192;
        f32x16 acc = {};
        #pragma unroll
        for (int kk = 0; kk < 8; ++kk) {
            bf16x8 af = *(const bf16x8*)(tp + kk * 16);
            int byteoff = (lid * 256 + kh * 16 + kk * 32) ^ ((lid & 15) << 4);
            bf16x8 bfr = *(const bf16x8*)(gs + byteoff);
            acc = __builtin_amdgcn_mfma_f32_32x32x16_bf16(af, bfr, acc, 0, 0, 0);
        }
        float* red = (float*)(smem + w * 8192);
        #pragma unroll
        for (int r = 0; r < 16; ++r) {
            int crow = (r & 3) + 8 * (r >> 2) + 4 * kh;
            red[crow * 32 + lid] = acc[r];
        }
    }
    __syncthreads();
    {
        float* r0 = (float*)smem;
        for (int k = tid; k < 1024; k += 256)
            part[(long)bid * 1024 + k] = r0[k] + r0[2048 + k] + r0[4096 + k] + r0[6144 + k];
    }
}

// GRU: 256 blocks (b = bid>>2, jc = bid&3) x 256 threads (j8 = tid>>5, u = tid&31).
// All operands LDS-staged in conflict-free layouts.
__global__ __launch_bounds__(256, 2) void k_gru(
    const float* __restrict__ part, const float* __restrict__ h,
    const float* __restrict__ adj, const float* __restrict__ msk,
    const float* __restrict__ b2T, const float* __restrict__ gWiT,
    const float* __restrict__ gWhT, const float* __restrict__ gbi,
    const float* __restrict__ gbh,
    float* __restrict__ hout, __hip_bfloat16* __restrict__ hout_bf) {
    __shared__ float hsh[1024], adjs[1024], wWiT[3072], wWhT[3072], b2s[1024];
    __shared__ float hsumL[256], mLs[256], gbs[192];
    const int tid = threadIdx.x, bid = blockIdx.x;
    const int b = bid >> 2, jc = bid & 3;
    const int j8 = tid >> 5, u = tid & 31, jg = jc * 8 + j8;
    for (int k = tid; k < 1024; k += 256) hsh[k] = h[b * 1024 + k];
    for (int k = tid; k < 1024; k += 256) adjs[k] = adj[b * 1024 + k];
    for (int k = tid; k < 3072; k += 256) wWiT[k] = gWiT[k];
    for (int k = tid; k < 3072; k += 256) wWhT[k] = gWhT[k];
    for (int k = tid; k < 1024; k += 256) b2s[k] = b2T[k];
    if (tid < 96) gbs[tid] = gbi[tid];
    else if (tid < 192) gbs[tid] = gbh[tid - 96];
    float ps = 0.f;
    #pragma unroll
    for (int ig = 0; ig < 8; ++ig)
        ps += part[((long)(b * 8 + ig)) * 1024 + jc * 256 + tid];
    __syncthreads();
    float hs = 0.f;     // hsum[jg][u] = sum_i adj[b,i,jg]*h[b,i,u]
    #pragma unroll
    for (int i = 0; i < 32; ++i) hs += adjs[i * 32 + jg] * hsh[i * 32 + u];
    hsumL[tid] = hs;
    __syncthreads();
    float m = ps;
    #pragma unroll
    for (int v = 0; v < 32; ++v) m += b2s[v * 32 + u] * hsumL[j8 * 32 + v];
    mLs[tid] = m;
    __syncthreads();
    float gi[3], gh[3];
    #pragma unroll
    for (int kb = 0; kb < 3; ++kb) {
        int k = kb * 32 + u;
        float a = gbs[k], c = gbs[96 + k];
        #pragma unroll
        for (int v = 0; v < 32; ++v) {
            a += mLs[j8 * 32 + v] * wWiT[v * 96 + k];
            c += hsh[jg * 32 + v] * wWhT[v * 96 + k];
        }
        gi[kb] = a; gh[kb] = c;
    }
    float r = sigf(gi[0] + gh[0]);
    float z = sigf(gi[1] + gh[1]);
    float n = tanhf(gi[2] + r * gh[2]);
    float hv = hsh[jg * 32 + u];
    float mm = msk[b * 32 + jg];
    float res = mm * ((1.f - z) * n + z * hv);
    hout[b * 1024 + jg * 32 + u] = res;
    hout_bf[b * 1024 + jg * 32 + u] = __float2bfloat16(res);
}

// Set2Set + final fc. grid = B, block = 128; transposed LSTM weights -> coalesced.
__global__ __launch_bounds__(128, 4) void k_s2s(
    const float* __restrict__ h, const float* __restrict__ msk,
    const float* __restrict__ lWiT, const float* __restrict__ lWhT,
    const float* __restrict__ lbi, const float* __restrict__ lbh,
    const float* __restrict__ Wf, const float* __restrict__ bf,
    float* __restrict__ out) {
    __shared__ float hsh[1024];
    __shared__ float mskk[32], qs[32], cs2[32], qstar[64], gsv[128], asv[32];
    const int tid = threadIdx.x, b = blockIdx.x;
    for (int k = tid; k < 1024; k += 128) hsh[k] = h[b * 1024 + k];
    if (tid < 32) { mskk[tid] = msk[b * 32 + tid]; qs[tid] = 0.f; cs2[tid] = 0.f; }
    if (tid < 64) qstar[tid] = 0.f;
    __syncthreads();
    for (int step = 0; step < 3; ++step) {
        {
            float g = lbi[tid] + lbh[tid];
            #pragma unroll
            for (int pp = 0; pp < 64; ++pp) g += qstar[pp] * lWiT[pp * 128 + tid];
            #pragma unroll
            for (int v = 0; v < 32; ++v) g += qs[v] * lWhT[v * 128 + tid];
            gsv[tid] = g;
        }
        __syncthreads();
        if (tid < 32) {
            float ci = sigf(gsv[32 + tid]) * cs2[tid] + sigf(gsv[tid]) * tanhf(gsv[64 + tid]);
            cs2[tid] = ci;
            qs[tid] = sigf(gsv[96 + tid]) * tanhf(ci);
        }
        __syncthreads();
        if (tid < 32) {
            float e = 0.f;
            #pragma unroll
            for (int v = 0; v < 32; ++v) e += hsh[tid * 32 + v] * qs[v];
            e = (mskk[tid] == 0.f) ? -INFINITY : e;
            float mx = e;
            for (int o = 16; o >= 1; o >>= 1) mx = fmaxf(mx, __shfl_xor(mx, o, 64));
            float a = expf(e - mx);
            float ss = a;
            for (int o = 16; o >= 1; o >>= 1) ss += __shfl_xor(ss, o, 64);
            asv[tid] = a / ss;
        }
        __syncthreads();
        if (tid < 32) {
            float rr = 0.f;
            #pragma unroll
            for (int nn = 0; nn < 32; ++nn) rr += asv[nn] * hsh[nn * 32 + tid] * mskk[nn];
            qstar[tid] = qs[tid];
            qstar[32 + tid] = rr;
        }
        __syncthreads();
    }
    if (tid < 64) {
        float v = qstar[tid] * Wf[tid];
        for (int o = 32; o >= 1; o >>= 1) v += __shfl_xor(v, o, 64);
        if (tid == 0) out[b] = v + bf[0];
    }
}

extern "C" void kernel_launch(void* const* d_in, const int* in_sizes, int n_in,
                              void* d_out, int out_size, void* d_ws, size_t ws_size,
                              hipStream_t stream) {
    const float* x    = (const float*)d_in[0];
    const float* edge = (const float*)d_in[1];
    const float* adj  = (const float*)d_in[2];
    const float* W_emb= (const float*)d_in[3];
    const float* b_emb= (const float*)d_in[4];
    const float* W1   = (const float*)d_in[5];
    const float* b1   = (const float*)d_in[6];
    const float* W2   = (const float*)d_in[7];
    const float* b2   = (const float*)d_in[8];
    const float* gWi  = (const float*)d_in[9];
    const float* gWh  = (const float*)d_in[10];
    const float* gbi  = (const float*)d_in[11];
    const float* gbh  = (const float*)d_in[12];
    const float* lWi  = (const float*)d_in[13];
    const float* lWh  = (const float*)d_in[14];
    const float* lbi  = (const float*)d_in[15];
    const float* lbh  = (const float*)d_in[16];
    const float* Wf   = (const float*)d_in[17];
    const float* bf   = (const float*)d_in[18];
    float* out = (float*)d_out;

    __hip_bfloat16* ta   = (__hip_bfloat16*)d_ws;       // 8388608 bf16
    __hip_bfloat16* BT   = ta + 8388608;                // 131072 bf16
    __hip_bfloat16* hbfA = BT + 131072;                 // 65536 bf16
    __hip_bfloat16* hbfB = hbfA + 65536;                // 65536 bf16
    float* hA   = (float*)(hbfB + 65536);               // 65536 f32
    float* hB   = hA + 65536;                           // 65536 f32
    float* mskp = hB + 65536;                           // 2048 f32
    float* part = mskp + 2048;                          // 524288 f32
    float* gWiT = part + 524288;                        // 3072
    float* gWhT = gWiT + 3072;                          // 3072
    float* b2T  = gWhT + 3072;                          // 1024
    float* lWiT = b2T + 1024;                           // 8192
    float* lWhT = lWiT + 8192;                          // 4096

    k_prep<<<512, 256, 0, stream>>>(edge, adj, W1, b1, x, W_emb, b_emb, W2,
                                    gWi, gWh, b2, lWi, lWh,
                                    ta, BT, hA, hbfA, mskp,
                                    gWiT, gWhT, b2T, lWiT, lWhT);
    float* hcur = hA; float* hnxt = hB;
    __hip_bfloat16* hbcur = hbfA; __hip_bfloat16* hbnxt = hbfB;
    for (int l = 0; l < 3; ++l) {
        k_layer<<<512, 256, 0, stream>>>(hbcur, BT, ta, part);
        k_gru<<<256, 256, 0, stream>>>(part, hcur, adj, mskp, b2T,
                                       gWiT, gWhT, gbi, gbh, hnxt, hbnxt);
        float* tf = hcur; hcur = hnxt; hnxt = tf;
        __hip_bfloat16* tb = hbcur; hbcur = hbnxt; hbnxt = tb;
    }
    k_s2s<<<64, 128, 0, stream>>>(hcur, mskp, lWiT, lWhT, lbi, lbh, Wf, bf, out);
}

// Round 6
// 108.870 us; speedup vs baseline: 5.9648x; 1.1814x over previous
//
#include <hip/hip_runtime.h>
#include <hip/hip_bf16.h>
#include <math.h>

typedef __attribute__((ext_vector_type(8))) short bf16x8;
typedef __attribute__((ext_vector_type(16))) float f32x16;

__device__ __forceinline__ float sigf(float x) { return 1.0f / (1.0f + expf(-x)); }

// prep: ta[row=b,i,j][c] = adj[b,i,j]*relu(edge@W1+b1) (bf16), h/hbf/msk,
//       BT[n][v] = W2[n&127][(n>>7)*32+v], transposed small weights.
// grid = 2048 x 256; block handles 32 edge rows; extra work on low bids.
__global__ __launch_bounds__(256, 4) void k_prep(
    const float* __restrict__ edge, const float* __restrict__ adj,
    const float* __restrict__ W1, const float* __restrict__ b1,
    const float* __restrict__ x, const float* __restrict__ W_emb,
    const float* __restrict__ b_emb, const float* __restrict__ W2,
    const float* __restrict__ gWi, const float* __restrict__ gWh,
    const float* __restrict__ b2, const float* __restrict__ lWi,
    const float* __restrict__ lWh,
    __hip_bfloat16* __restrict__ ta, __hip_bfloat16* __restrict__ BT,
    float* __restrict__ h, __hip_bfloat16* __restrict__ hbf, float* __restrict__ msk,
    float* __restrict__ gWiT, float* __restrict__ gWhT, float* __restrict__ b2T,
    float* __restrict__ lWiT, float* __restrict__ lWhT) {
    __shared__ float es[512];      // 32 rows x 16
    __shared__ float adjs2[32];
    __shared__ float xs[256];
    const int tid = threadIdx.x, bid = blockIdx.x;
    const int c = tid & 127, g = tid >> 7;
    float wr[16];
    #pragma unroll
    for (int v = 0; v < 16; ++v) wr[v] = W1[v * 128 + c];
    const float b1c = b1[c];
    if (tid < 128) ((float4*)es)[tid] = ((const float4*)(edge + (long)bid * 512))[tid];
    if (tid >= 128 && tid < 160) adjs2[tid - 128] = adj[bid * 32 + (tid - 128)];
    if (bid < 256 && tid < 256) xs[tid] = x[bid * 256 + tid];
    __syncthreads();
    {   // edge MLP: rows g*16 .. g*16+15, col c
        const int r0 = g * 16;
        #pragma unroll
        for (int r = 0; r < 16; ++r) {
            const float* er = es + (r0 + r) * 16;
            float acc = b1c;
            #pragma unroll
            for (int k = 0; k < 16; ++k) acc += er[k] * wr[k];
            float av = adjs2[r0 + r];
            ta[((long)bid * 32 + r0 + r) * 128 + c] = __float2bfloat16(av * fmaxf(acc, 0.f));
        }
    }
    if (bid < 256) {            // embed: 8 rows of (b*N+n)
        int r = tid >> 5, u = tid & 31;
        int rowe = bid * 8 + r;
        float acc = b_emb[u];
        #pragma unroll
        for (int k = 0; k < 32; ++k) acc += xs[r * 32 + k] * W_emb[k * 32 + u];
        h[rowe * 32 + u] = acc;
        hbf[rowe * 32 + u] = __float2bfloat16(acc);
        if (u == 0) {
            float s = 0.f;
            #pragma unroll
            for (int k = 0; k < 32; ++k) s += xs[r * 32 + k];
            msk[rowe] = (s > 0.f) ? 1.f : 0.f;
        }
    } else if (bid < 384) {     // BT
        int base = (bid - 256) * 1024;
        #pragma unroll
        for (int q = 0; q < 4; ++q) {
            int idx = base + q * 256 + tid;
            int n = idx >> 5, v = idx & 31;
            BT[idx] = __float2bfloat16(W2[(n & 127) * 1024 + (n >> 7) * 32 + v]);
        }
    } else if (bid == 384) {    // transposed weights
        for (int idx = tid; idx < 3072; idx += 256) gWiT[(idx & 31) * 96 + (idx >> 5)] = gWi[idx];
        for (int idx = tid; idx < 3072; idx += 256) gWhT[(idx & 31) * 96 + (idx >> 5)] = gWh[idx];
        for (int idx = tid; idx < 1024; idx += 256) b2T[(idx & 31) * 32 + (idx >> 5)] = b2[idx];
        for (int idx = tid; idx < 8192; idx += 256) lWiT[(idx & 63) * 128 + (idx >> 6)] = lWi[idx];
        for (int idx = tid; idx < 4096; idx += 256) lWhT[(idx & 31) * 128 + (idx >> 5)] = lWh[idx];
    }
}

// per-layer: grid 256 = (b, ig) ig<4, 8 i's each. G into LDS (M=8 MFMA, 64KB),
// then msg MFMA (2 i's per wave into one acc), 4-wave reduce -> part.
__global__ __launch_bounds__(256, 2) void k_layer(
    const __hip_bfloat16* __restrict__ hbf, const __hip_bfloat16* __restrict__ BT,
    const __hip_bfloat16* __restrict__ ta, float* __restrict__ part) {
    __shared__ __align__(16) char smem[65536];
    const int tid = threadIdx.x, bid = blockIdx.x;
    const int w = tid >> 6, l = tid & 63, lid = l & 31, kh = l >> 5;
    const int b = bid >> 2, ig = bid & 3;
    // ---- G phase: G_{b, ig*8 + 0..7} ----
    {
        const short* hp = (const short*)hbf + ((b * 32 + ig * 8 + (lid & 7)) * 32 + kh * 8);
        bf16x8 a0 = *(const bf16x8*)hp;
        bf16x8 a1 = *(const bf16x8*)(hp + 16);
        const short* bbase = (const short*)BT;
        const int nt0 = w * 32;
        const short* bp = bbase + (nt0 * 32 + lid) * 32 + kh * 8;
        bf16x8 nb0 = *(const bf16x8*)bp;
        bf16x8 nb1 = *(const bf16x8*)(bp + 16);
        char* base = smem + 4 * kh * 8192;
        for (int q = 0; q < 32; ++q) {
            bf16x8 b0 = nb0, b1v = nb1;
            if (q < 31) {
                const short* bp2 = bbase + ((nt0 + q + 1) * 32 + lid) * 32 + kh * 8;
                nb0 = *(const bf16x8*)bp2;
                nb1 = *(const bf16x8*)(bp2 + 16);
            }
            f32x16 accg = {};
            accg = __builtin_amdgcn_mfma_f32_32x32x16_bf16(a0, b0, accg, 0, 0, 0);
            accg = __builtin_amdgcn_mfma_f32_32x32x16_bf16(a1, b1v, accg, 0, 0, 0);
            int n = (nt0 + q) * 32 + lid;
            int u = n >> 7, cc = n & 127;
            int byteoff = (u * 256 + cc * 2) ^ ((u & 15) << 4);
            #pragma unroll
            for (int r = 0; r < 4; ++r)   // crow = r + 4*kh -> i-slot
                *(__hip_bfloat16*)(base + r * 8192 + byteoff) = __float2bfloat16(accg[r]);
        }
    }
    __syncthreads();
    // ---- msg phase: wave w accumulates i = 2w, 2w+1 ----
    {
        f32x16 acc = {};
        #pragma unroll
        for (int ii = 0; ii < 2; ++ii) {
            int i = w * 2 + ii;
            long bi = b * 32 + ig * 8 + i;
            const short* tp = (const short*)ta + (bi * 32 + lid) * 128 + kh * 8;
            char* gs = smem + i * 8192;
            #pragma unroll
            for (int kk = 0; kk < 8; ++kk) {
                bf16x8 af = *(const bf16x8*)(tp + kk * 16);
                int byteoff = (lid * 256 + kh * 16 + kk * 32) ^ ((lid & 15) << 4);
                bf16x8 bfr = *(const bf16x8*)(gs + byteoff);
                acc = __builtin_amdgcn_mfma_f32_32x32x16_bf16(af, bfr, acc, 0, 0, 0);
            }
        }
        float* red = (float*)(smem + (w * 2) * 8192);   // own region only
        #pragma unroll
        for (int r = 0; r < 16; ++r) {
            int crow = (r & 3) + 8 * (r >> 2) + 4 * kh;
            red[crow * 32 + lid] = acc[r];
        }
    }
    __syncthreads();
    {
        float* r0 = (float*)smem;
        for (int k = tid; k < 1024; k += 256)
            part[(long)bid * 1024 + k] = r0[k] + r0[4096 + k] + r0[8192 + k] + r0[12288 + k];
    }
}

// GRU: 256 blocks (b = bid>>2, jc = bid&3) x 256 threads; LDS-staged, conflict-free.
__global__ __launch_bounds__(256, 2) void k_gru(
    const float* __restrict__ part, const float* __restrict__ h,
    const float* __restrict__ adj, const float* __restrict__ msk,
    const float* __restrict__ b2T, const float* __restrict__ gWiT,
    const float* __restrict__ gWhT, const float* __restrict__ gbi,
    const float* __restrict__ gbh,
    float* __restrict__ hout, __hip_bfloat16* __restrict__ hout_bf) {
    __shared__ float hsh[1024], adjs[1024], wWiT[3072], wWhT[3072], b2s[1024];
    __shared__ float hsumL[256], mLs[256], gbs[192];
    const int tid = threadIdx.x, bid = blockIdx.x;
    const int b = bid >> 2, jc = bid & 3;
    const int j8 = tid >> 5, u = tid & 31, jg = jc * 8 + j8;
    for (int k = tid; k < 1024; k += 256) hsh[k] = h[b * 1024 + k];
    for (int k = tid; k < 1024; k += 256) adjs[k] = adj[b * 1024 + k];
    for (int k = tid; k < 3072; k += 256) wWiT[k] = gWiT[k];
    for (int k = tid; k < 3072; k += 256) wWhT[k] = gWhT[k];
    for (int k = tid; k < 1024; k += 256) b2s[k] = b2T[k];
    if (tid < 96) gbs[tid] = gbi[tid];
    else if (tid < 192) gbs[tid] = gbh[tid - 96];
    float ps = 0.f;
    #pragma unroll
    for (int ig = 0; ig < 4; ++ig)
        ps += part[((long)(b * 4 + ig)) * 1024 + jc * 256 + tid];
    __syncthreads();
    float hs = 0.f;     // hsum[jg][u] = sum_i adj[b,i,jg]*h[b,i,u]
    #pragma unroll
    for (int i = 0; i < 32; ++i) hs += adjs[i * 32 + jg] * hsh[i * 32 + u];
    hsumL[tid] = hs;
    __syncthreads();
    float m = ps;
    #pragma unroll
    for (int v = 0; v < 32; ++v) m += b2s[v * 32 + u] * hsumL[j8 * 32 + v];
    mLs[tid] = m;
    __syncthreads();
    float gi[3], gh[3];
    #pragma unroll
    for (int kb = 0; kb < 3; ++kb) {
        int k = kb * 32 + u;
        float a = gbs[k], c = gbs[96 + k];
        #pragma unroll
        for (int v = 0; v < 32; ++v) {
            a += mLs[j8 * 32 + v] * wWiT[v * 96 + k];
            c += hsh[jg * 32 + v] * wWhT[v * 96 + k];
        }
        gi[kb] = a; gh[kb] = c;
    }
    float r = sigf(gi[0] + gh[0]);
    float z = sigf(gi[1] + gh[1]);
    float n = tanhf(gi[2] + r * gh[2]);
    float hv = hsh[jg * 32 + u];
    float mm = msk[b * 32 + jg];
    float res = mm * ((1.f - z) * n + z * hv);
    hout[b * 1024 + jg * 32 + u] = res;
    hout_bf[b * 1024 + jg * 32 + u] = __float2bfloat16(res);
}

// Set2Set + final fc. grid = B, block = 128.
__global__ __launch_bounds__(128, 4) void k_s2s(
    const float* __restrict__ h, const float* __restrict__ msk,
    const float* __restrict__ lWiT, const float* __restrict__ lWhT,
    const float* __restrict__ lbi, const float* __restrict__ lbh,
    const float* __restrict__ Wf, const float* __restrict__ bf,
    float* __restrict__ out) {
    __shared__ float hsh[1024];
    __shared__ float mskk[32], qs[32], cs2[32], qstar[64], gsv[128], asv[32];
    const int tid = threadIdx.x, b = blockIdx.x;
    for (int k = tid; k < 1024; k += 128) hsh[k] = h[b * 1024 + k];
    if (tid < 32) { mskk[tid] = msk[b * 32 + tid]; qs[tid] = 0.f; cs2[tid] = 0.f; }
    if (tid < 64) qstar[tid] = 0.f;
    __syncthreads();
    for (int step = 0; step < 3; ++step) {
        {
            float g = lbi[tid] + lbh[tid];
            #pragma unroll
            for (int pp = 0; pp < 64; ++pp) g += qstar[pp] * lWiT[pp * 128 + tid];
            #pragma unroll
            for (int v = 0; v < 32; ++v) g += qs[v] * lWhT[v * 128 + tid];
            gsv[tid] = g;
        }
        __syncthreads();
        if (tid < 32) {
            float ci = sigf(gsv[32 + tid]) * cs2[tid] + sigf(gsv[tid]) * tanhf(gsv[64 + tid]);
            cs2[tid] = ci;
            qs[tid] = sigf(gsv[96 + tid]) * tanhf(ci);
        }
        __syncthreads();
        if (tid < 32) {
            float e = 0.f;
            #pragma unroll
            for (int v = 0; v < 32; ++v) e += hsh[tid * 32 + v] * qs[v];
            e = (mskk[tid] == 0.f) ? -INFINITY : e;
            float mx = e;
            for (int o = 16; o >= 1; o >>= 1) mx = fmaxf(mx, __shfl_xor(mx, o, 64));
            float a = expf(e - mx);
            float ss = a;
            for (int o = 16; o >= 1; o >>= 1) ss += __shfl_xor(ss, o, 64);
            asv[tid] = a / ss;
        }
        __syncthreads();
        if (tid < 32) {
            float rr = 0.f;
            #pragma unroll
            for (int nn = 0; nn < 32; ++nn) rr += asv[nn] * hsh[nn * 32 + tid] * mskk[nn];
            qstar[tid] = qs[tid];
            qstar[32 + tid] = rr;
        }
        __syncthreads();
    }
    if (tid < 64) {
        float v = qstar[tid] * Wf[tid];
        for (int o = 32; o >= 1; o >>= 1) v += __shfl_xor(v, o, 64);
        if (tid == 0) out[b] = v + bf[0];
    }
}

extern "C" void kernel_launch(void* const* d_in, const int* in_sizes, int n_in,
                              void* d_out, int out_size, void* d_ws, size_t ws_size,
                              hipStream_t stream) {
    const float* x    = (const float*)d_in[0];
    const float* edge = (const float*)d_in[1];
    const float* adj  = (const float*)d_in[2];
    const float* W_emb= (const float*)d_in[3];
    const float* b_emb= (const float*)d_in[4];
    const float* W1   = (const float*)d_in[5];
    const float* b1   = (const float*)d_in[6];
    const float* W2   = (const float*)d_in[7];
    const float* b2   = (const float*)d_in[8];
    const float* gWi  = (const float*)d_in[9];
    const float* gWh  = (const float*)d_in[10];
    const float* gbi  = (const float*)d_in[11];
    const float* gbh  = (const float*)d_in[12];
    const float* lWi  = (const float*)d_in[13];
    const float* lWh  = (const float*)d_in[14];
    const float* lbi  = (const float*)d_in[15];
    const float* lbh  = (const float*)d_in[16];
    const float* Wf   = (const float*)d_in[17];
    const float* bf   = (const float*)d_in[18];
    float* out = (float*)d_out;

    __hip_bfloat16* ta   = (__hip_bfloat16*)d_ws;       // 8388608 bf16
    __hip_bfloat16* BT   = ta + 8388608;                // 131072 bf16
    __hip_bfloat16* hbfA = BT + 131072;                 // 65536 bf16
    __hip_bfloat16* hbfB = hbfA + 65536;                // 65536 bf16
    float* hA   = (float*)(hbfB + 65536);               // 65536 f32
    float* hB   = hA + 65536;                           // 65536 f32
    float* mskp = hB + 65536;                           // 2048 f32
    float* part = mskp + 2048;                          // 262144 f32
    float* gWiT = part + 262144;                        // 3072
    float* gWhT = gWiT + 3072;                          // 3072
    float* b2T  = gWhT + 3072;                          // 1024
    float* lWiT = b2T + 1024;                           // 8192
    float* lWhT = lWiT + 8192;                          // 4096

    k_prep<<<2048, 256, 0, stream>>>(edge, adj, W1, b1, x, W_emb, b_emb, W2,
                                     gWi, gWh, b2, lWi, lWh,
                                     ta, BT, hA, hbfA, mskp,
                                     gWiT, gWhT, b2T, lWiT, lWhT);
    float* hcur = hA; float* hnxt = hB;
    __hip_bfloat16* hbcur = hbfA; __hip_bfloat16* hbnxt = hbfB;
    for (int l = 0; l < 3; ++l) {
        k_layer<<<256, 256, 0, stream>>>(hbcur, BT, ta, part);
        k_gru<<<256, 256, 0, stream>>>(part, hcur, adj, mskp, b2T,
                                       gWiT, gWhT, gbi, gbh, hnxt, hbnxt);
        float* tf = hcur; hcur = hnxt; hnxt = tf;
        __hip_bfloat16* tb = hbcur; hbcur = hbnxt; hbnxt = tb;
    }
    k_s2s<<<64, 128, 0, stream>>>(hcur, mskp, lWiT, lWhT, lbi, lbh, Wf, bf, out);
}